// Round 16
// baseline (147.969 us; speedup 1.0000x reference)
//
#include <hip/hip_runtime.h>
#include <hip/hip_fp16.h>

typedef _Float16 f16x8 __attribute__((ext_vector_type(8)));
typedef float f32x4 __attribute__((ext_vector_type(4)));

// ---------------------------------------------------------------------------
// 3-layer GCN, ELL-gather (ushort, sentinel-padded), fp16 intermediates, MFMA.
//   deg32[i*16] : padded atomic counters (one 64B line each)
//   ell[i*64+c] : ushort src list; unwritten slots = sentinel N (zero row)
//   g = rsqrt(deg+1) .* (x@W)   (scale fused into every GEMM epilogue)
//   layer: out[i] = maybe_relu( dis_i * ( g[i] + sum_src g[src] ) + b )
// r16: 8B/lane paired gathers — one VMEM instruction fetches 2 rows (fused
// aggr: 32-lane parity halves + shfl_xor combine) or 4 rows (final aggr:
// 16-lane groups), halving gather instruction count.
// Rejected: grid.sync (r12, ~120us/sync), multi-node serial waves (r9),
// XCD-partitioned fill (r15, null), MLP-deeper fill (r8, null).
// ---------------------------------------------------------------------------

__global__ void k_init(int* __restrict__ deg32, int nDeg,
                       unsigned int* __restrict__ ellw, int nEllw,
                       unsigned int pat) {
    int i = blockIdx.x * blockDim.x + threadIdx.x;
    if (i < nDeg) deg32[i] = 0;
    if (i < nEllw) ellw[i] = pat;  // sentinel N in both ushort halves
}

__global__ __launch_bounds__(256) void k_ellfill(const int* __restrict__ src,
                                                 const int* __restrict__ dst,
                                                 int* __restrict__ deg32,
                                                 unsigned short* __restrict__ ell, int E) {
    int e = blockIdx.x * blockDim.x + threadIdx.x;
    if (e >= E) return;
    int d = dst[e];
    int c = atomicAdd(&deg32[d << 4], 1);
    if (c < 64) ell[(size_t)d * 64 + c] = (unsigned short)src[e];
}

// ---------------------------------------------------------------------------
// Standalone MFMA GEMM (layer 1 only): G[N+1][128] = dis .* (X_f32@W1).
// ---------------------------------------------------------------------------
__global__ __launch_bounds__(256) void k_gemm1(const float* __restrict__ X,
                                               const float* __restrict__ W,
                                               const int* __restrict__ deg32,
                                               _Float16* __restrict__ G, int N) {
    if (blockIdx.x == 0 && threadIdx.x < 64)
        ((int*)(G + (size_t)N * 128))[threadIdx.x] = 0;  // zero row N

    const int lane = threadIdx.x & 63;
    const int wv = threadIdx.x >> 6;
    const int lo = lane & 15;
    const int kg = lane >> 4;
    const int colbase = wv * 32;

    f16x8 b[4][2];
#pragma unroll
    for (int t = 0; t < 4; ++t)
#pragma unroll
        for (int u = 0; u < 2; ++u)
#pragma unroll
            for (int j = 0; j < 8; ++j)
                b[t][u][j] = (_Float16)W[(size_t)(t * 32 + kg * 8 + j) * 128 +
                                         colbase + u * 16 + lo];

    const int nslabs = N >> 4;
    for (int slab = blockIdx.x; slab < nslabs; slab += gridDim.x) {
        const int arow = slab * 16 + lo;
        f32x4 acc[2];
        acc[0] = (f32x4)0.0f;
        acc[1] = (f32x4)0.0f;
#pragma unroll
        for (int t = 0; t < 4; ++t) {
            const float4* xp = (const float4*)&X[(size_t)arow * 128 + t * 32 + kg * 8];
            float4 u0 = xp[0], u1 = xp[1];
            f16x8 a;
            a[0] = (_Float16)u0.x; a[1] = (_Float16)u0.y;
            a[2] = (_Float16)u0.z; a[3] = (_Float16)u0.w;
            a[4] = (_Float16)u1.x; a[5] = (_Float16)u1.y;
            a[6] = (_Float16)u1.z; a[7] = (_Float16)u1.w;
#pragma unroll
            for (int u = 0; u < 2; ++u)
                acc[u] = __builtin_amdgcn_mfma_f32_16x16x32_f16(a, b[t][u], acc[u], 0, 0, 0);
        }

        float ds[4];
#pragma unroll
        for (int r = 0; r < 4; ++r)
            ds[r] = rsqrtf((float)(deg32[(slab * 16 + kg * 4 + r) << 4] + 1));

#pragma unroll
        for (int u = 0; u < 2; ++u) {
            int col = colbase + u * 16 + lo;
#pragma unroll
            for (int r = 0; r < 4; ++r) {
                int row = slab * 16 + kg * 4 + r;
                G[(size_t)row * 128 + col] = (_Float16)(acc[u][r] * ds[r]);
            }
        }
    }
}

// ---------------------------------------------------------------------------
// Fused aggregation + next-layer GEMM. 1024 threads = 16 waves.
// Aggr: wave wv -> node base+wv. Paired gather: lane halves take even/odd
// edges; lane hl of each half loads 8B (features [4hl,4hl+4)) -> one VMEM
// instruction fetches TWO 256B rows. shfl_xor(32) combines parities.
// -> LDS As[16][136]; then BN/16 waves run the 16-row MFMA + scaled epilogue.
// ---------------------------------------------------------------------------
template <int BN>
__global__ __launch_bounds__(1024, 8) void k_aggr_gemm(
    const int* __restrict__ deg32, const unsigned short* __restrict__ ell,
    const __half* __restrict__ gin, const float* __restrict__ bias,
    const float* __restrict__ W, _Float16* __restrict__ gout, int N) {
    __shared__ _Float16 As[16][136];

    const int wv = threadIdx.x >> 6;   // 0..15
    const int lane = threadIdx.x & 63;
    const int hi = lane >> 5;          // edge-parity class
    const int hl = lane & 31;          // feature slot: [4hl, 4hl+4)

    if (blockIdx.x == 0 && threadIdx.x < BN / 2)
        ((int*)(gout + (size_t)N * BN))[threadIdx.x] = 0;  // zero row N

    const int base = blockIdx.x * 16;
    const int wid = base + wv;
    {
        int d = deg32[wid << 4];
        int dc = min(d, 64);
        int dp = (dc + 15) & ~15;

        const _Float16* gph = (const _Float16*)gin;
        const uint4* rowq = (const uint4*)&ell[(size_t)wid * 64];

        __half2 s0 = __float2half2_rn(0.f), s1 = s0, s2 = s0, s3 = s0;

        for (int j = 0; j < dp; j += 16) {
            uint4 r0 = rowq[j >> 3];
            uint4 r1 = rowq[(j >> 3) + 1];
            unsigned w[8] = {r0.x, r0.y, r0.z, r0.w, r1.x, r1.y, r1.z, r1.w};
            uint2 v[8];
#pragma unroll
            for (int t = 0; t < 8; ++t) {
                unsigned idx = (w[t] >> (hi * 16)) & 0xFFFFu;  // edge 2t+hi
                v[t] = *(const uint2*)&gph[(size_t)idx * 128 + hl * 4];
            }
#pragma unroll
            for (int t = 0; t < 8; t += 2) {
                s0 = __hadd2(s0, *(__half2*)&v[t].x);
                s1 = __hadd2(s1, *(__half2*)&v[t].y);
                s2 = __hadd2(s2, *(__half2*)&v[t + 1].x);
                s3 = __hadd2(s3, *(__half2*)&v[t + 1].y);
            }
        }

        __half2 sA = __hadd2(s0, s2);  // features 4hl..4hl+1 (my parity)
        __half2 sB = __hadd2(s1, s3);  // features 4hl+2..4hl+3
        int xA = __shfl_xor(*(int*)&sA, 32);
        int xB = __shfl_xor(*(int*)&sB, 32);
        sA = __hadd2(sA, *(__half2*)&xA);
        sB = __hadd2(sB, *(__half2*)&xB);

        if (hi == 0) {
            float2 fA = __half22float2(sA), fB = __half22float2(sB);
            uint2 sv = *(const uint2*)&gph[(size_t)wid * 128 + hl * 4];
            float2 vA = __half22float2(*(__half2*)&sv.x);
            float2 vB = __half22float2(*(__half2*)&sv.y);
            float di = rsqrtf((float)(d + 1));
            float4 bv = *(const float4*)&bias[hl * 4];
            float o0 = fmaxf(di * (fA.x + vA.x) + bv.x, 0.f);
            float o1 = fmaxf(di * (fA.y + vA.y) + bv.y, 0.f);
            float o2 = fmaxf(di * (fB.x + vB.x) + bv.z, 0.f);
            float o3 = fmaxf(di * (fB.y + vB.y) + bv.w, 0.f);
            __half2 h0 = __float22half2_rn(make_float2(o0, o1));
            __half2 h1 = __float22half2_rn(make_float2(o2, o3));
            uint2 ov;
            ov.x = *(unsigned*)&h0;
            ov.y = *(unsigned*)&h1;
            *(uint2*)&As[wv][hl * 4] = ov;
        }
    }
    __syncthreads();

    if (wv < BN / 16) {
        const int lo = lane & 15;
        const int kg = lane >> 4;
        const int col = wv * 16 + lo;

        f16x8 b[4];
#pragma unroll
        for (int t = 0; t < 4; ++t)
#pragma unroll
            for (int j = 0; j < 8; ++j)
                b[t][j] = (_Float16)W[(size_t)(t * 32 + kg * 8 + j) * BN + col];

        f32x4 acc = (f32x4)0.0f;
#pragma unroll
        for (int t = 0; t < 4; ++t) {
            f16x8 a = *(const f16x8*)&As[lo][t * 32 + kg * 8];
            acc = __builtin_amdgcn_mfma_f32_16x16x32_f16(a, b[t], acc, 0, 0, 0);
        }

#pragma unroll
        for (int r = 0; r < 4; ++r) {
            int row = base + kg * 4 + r;
            float ds = rsqrtf((float)(deg32[row << 4] + 1));
            gout[(size_t)row * BN + col] = (_Float16)(acc[r] * ds);
        }
    }
}

// ---------------------------------------------------------------------------
// Final aggregation (F=64): FOUR nodes per wave (16-lane groups, 8B/lane) —
// one VMEM instruction gathers 4 rows. fp32 out, no relu, no cross-lane
// combine (each 16-lane group owns its node's full 128B row).
// ---------------------------------------------------------------------------
__global__ __launch_bounds__(256) void k_aggr_final(const int* __restrict__ deg32,
                                                    const unsigned short* __restrict__ ell,
                                                    const __half* __restrict__ g,
                                                    const float* __restrict__ bias,
                                                    float* __restrict__ out, int N) {
    int wid = blockIdx.x * 16 + (threadIdx.x >> 4);
    int ql = threadIdx.x & 15;  // features [4ql, 4ql+4)
    if (wid >= N) return;
    int d = deg32[wid << 4];
    int dc = min(d, 64);
    int dp = (dc + 15) & ~15;

    const _Float16* gph = (const _Float16*)g;
    const uint4* rowq = (const uint4*)&ell[(size_t)wid * 64];

    __half2 s0 = __float2half2_rn(0.f), s1 = s0, s2 = s0, s3 = s0;

    for (int j = 0; j < dp; j += 16) {
        uint4 r0 = rowq[j >> 3];
        uint4 r1 = rowq[(j >> 3) + 1];
        unsigned w[8] = {r0.x, r0.y, r0.z, r0.w, r1.x, r1.y, r1.z, r1.w};
        uint2 v[16];
#pragma unroll
        for (int t = 0; t < 16; ++t) {
            unsigned idx = (w[t >> 1] >> ((t & 1) * 16)) & 0xFFFFu;
            v[t] = *(const uint2*)&gph[(size_t)idx * 64 + ql * 4];
        }
#pragma unroll
        for (int t = 0; t < 16; t += 2) {
            s0 = __hadd2(s0, *(__half2*)&v[t].x);
            s1 = __hadd2(s1, *(__half2*)&v[t].y);
            s2 = __hadd2(s2, *(__half2*)&v[t + 1].x);
            s3 = __hadd2(s3, *(__half2*)&v[t + 1].y);
        }
    }

    float2 fA = __half22float2(__hadd2(s0, s2));
    float2 fB = __half22float2(__hadd2(s1, s3));
    uint2 sv = *(const uint2*)&gph[(size_t)wid * 64 + ql * 4];
    float2 vA = __half22float2(*(__half2*)&sv.x);
    float2 vB = __half22float2(*(__half2*)&sv.y);

    float di = rsqrtf((float)(d + 1));
    float4 bv = *(const float4*)&bias[ql * 4];
    float4 o;
    o.x = di * (fA.x + vA.x) + bv.x;
    o.y = di * (fA.y + vA.y) + bv.y;
    o.z = di * (fB.x + vB.x) + bv.z;
    o.w = di * (fB.y + vB.y) + bv.w;
    *(float4*)&out[(size_t)wid * 64 + ql * 4] = o;
}

extern "C" void kernel_launch(void* const* d_in, const int* in_sizes, int n_in,
                              void* d_out, int out_size, void* d_ws, size_t ws_size,
                              hipStream_t stream) {
    const float* x = (const float*)d_in[0];
    const int* ei = (const int*)d_in[1];
    const float* W1 = (const float*)d_in[2];
    const float* b1 = (const float*)d_in[3];
    const float* W2 = (const float*)d_in[4];
    const float* b2 = (const float*)d_in[5];
    const float* W3 = (const float*)d_in[6];
    const float* b3 = (const float*)d_in[7];

    const int N = in_sizes[0] / 128;  // 50000
    const int E = in_sizes[1] / 2;    // 640000
    const int* src = ei;
    const int* dst = ei + E;

    auto align512 = [](size_t v) { return (v + 511) & ~(size_t)511; };
    char* p = (char*)d_ws;
    int* deg32 = (int*)p;                      p += align512((size_t)(N + 1) * 16 * 4);
    unsigned short* ell = (unsigned short*)p;  p += align512((size_t)N * 64 * 2);
    __half* bufA = (__half*)p;                 p += align512((size_t)(N + 1) * 128 * 2);
    __half* bufB = (__half*)p;

    // 1) zero padded degree counters + sentinel-fill ELL
    int nDeg = (N + 1) * 16;
    int nEllw = N * 32;  // ELL dwords
    unsigned int pat = ((unsigned)N << 16) | (unsigned)N;
    int initThreads = nDeg > nEllw ? nDeg : nEllw;
    k_init<<<(initThreads + 255) / 256, 256, 0, stream>>>(deg32, nDeg,
                                                          (unsigned int*)ell, nEllw, pat);
    // 2) ELL fill (padded atomic cursors)
    k_ellfill<<<(E + 255) / 256, 256, 0, stream>>>(src, dst, deg32, ell, E);
    // 3) gemm1: g1 = dis .* (x@W1) -> bufA
    k_gemm1<<<512, 256, 0, stream>>>(x, W1, deg32, (_Float16*)bufA, N);
    // 4) fused aggr1 + gemm2 -> bufB
    k_aggr_gemm<128><<<N / 16, 1024, 0, stream>>>(deg32, ell, bufA, b1, W2,
                                                  (_Float16*)bufB, N);
    // 5) fused aggr2 + gemm3 -> bufA (64-wide)
    k_aggr_gemm<64><<<N / 16, 1024, 0, stream>>>(deg32, ell, bufB, b2, W3,
                                                 (_Float16*)bufA, N);
    // 6) final aggregation -> fp32 output
    k_aggr_final<<<(N + 15) / 16, 256, 0, stream>>>(deg32, ell, bufA, b3,
                                                    (float*)d_out, N);
}

// Round 17
// 137.245 us; speedup vs baseline: 1.0781x; 1.0781x over previous
//
#include <hip/hip_runtime.h>
#include <hip/hip_fp16.h>

typedef _Float16 f16x8 __attribute__((ext_vector_type(8)));
typedef float f32x4 __attribute__((ext_vector_type(4)));

// ---------------------------------------------------------------------------
// 3-layer GCN, ELL-gather (ushort, sentinel-padded), fp16 intermediates, MFMA.
//   deg32[i*16] : padded atomic counters (one 64B line each)
//   ell[i*64+c] : ushort src list; unwritten slots = sentinel N (zero row)
//   g = rsqrt(deg+1) .* (x@W)   (scale fused into every GEMM epilogue)
//   layer: out[i] = maybe_relu( dis_i * ( g[i] + sum_src g[src] ) + b )
// r17 = r15 exact revert (best measured, 136.2us).
// Rejected fronts (measured): grid.sync (r12, ~120us/sync on 8 XCDs);
// serial multi-node waves (r9, -66%); XCD-partitioned fill (r15, null);
// MLP-deeper fill (r8, null); paired 8B/lane gathers (r16, -9% — 4B/lane
// full-row gather is the coalescing sweet spot).
// ---------------------------------------------------------------------------

__global__ void k_init(int* __restrict__ deg32, int nDeg,
                       unsigned int* __restrict__ ellw, int nEllw,
                       unsigned int pat) {
    int i = blockIdx.x * blockDim.x + threadIdx.x;
    if (i < nDeg) deg32[i] = 0;
    if (i < nEllw) ellw[i] = pat;  // sentinel N in both ushort halves
}

// XCD-partitioned fill: blocks with (blockIdx&7)==k commit nodes with
// (dst&7)==k (round-robin blockIdx->XCD). Edge list is L2-resident, the 8x
// rescan is ~free; measured equal to the simple one-pass fill.
__global__ __launch_bounds__(256) void k_ellfill(const int* __restrict__ src,
                                                 const int* __restrict__ dst,
                                                 int* __restrict__ deg32,
                                                 unsigned short* __restrict__ ell, int E) {
    const int part = blockIdx.x & 7;
    const int setId = blockIdx.x >> 3;
    const int nset = gridDim.x >> 3;
    const int tid = setId * blockDim.x + threadIdx.x;
    const int T = nset * blockDim.x;

    const int e4n = E >> 2;
    const int4* d4p = (const int4*)dst;
    const int4* s4p = (const int4*)src;
    for (int q = tid; q < e4n; q += T) {
        int4 d4 = d4p[q];
        int4 s4 = s4p[q];
        int dd[4] = {d4.x, d4.y, d4.z, d4.w};
        int ss[4] = {s4.x, s4.y, s4.z, s4.w};
#pragma unroll
        for (int t = 0; t < 4; ++t) {
            if ((dd[t] & 7) == part) {
                int c = atomicAdd(&deg32[dd[t] << 4], 1);
                if (c < 64) ell[(size_t)dd[t] * 64 + c] = (unsigned short)ss[t];
            }
        }
    }
    for (int e = (e4n << 2) + tid; e < E; e += T) {
        int d = dst[e];
        if ((d & 7) == part) {
            int c = atomicAdd(&deg32[d << 4], 1);
            if (c < 64) ell[(size_t)d * 64 + c] = (unsigned short)src[e];
        }
    }
}

// ---------------------------------------------------------------------------
// Standalone MFMA GEMM (layer 1 only): G[N+1][128] = dis .* (X_f32@W1).
// ---------------------------------------------------------------------------
__global__ __launch_bounds__(256) void k_gemm1(const float* __restrict__ X,
                                               const float* __restrict__ W,
                                               const int* __restrict__ deg32,
                                               _Float16* __restrict__ G, int N) {
    if (blockIdx.x == 0 && threadIdx.x < 64)
        ((int*)(G + (size_t)N * 128))[threadIdx.x] = 0;  // zero row N

    const int lane = threadIdx.x & 63;
    const int wv = threadIdx.x >> 6;
    const int lo = lane & 15;
    const int kg = lane >> 4;
    const int colbase = wv * 32;

    f16x8 b[4][2];
#pragma unroll
    for (int t = 0; t < 4; ++t)
#pragma unroll
        for (int u = 0; u < 2; ++u)
#pragma unroll
            for (int j = 0; j < 8; ++j)
                b[t][u][j] = (_Float16)W[(size_t)(t * 32 + kg * 8 + j) * 128 +
                                         colbase + u * 16 + lo];

    const int nslabs = N >> 4;
    for (int slab = blockIdx.x; slab < nslabs; slab += gridDim.x) {
        const int arow = slab * 16 + lo;
        f32x4 acc[2];
        acc[0] = (f32x4)0.0f;
        acc[1] = (f32x4)0.0f;
#pragma unroll
        for (int t = 0; t < 4; ++t) {
            const float4* xp = (const float4*)&X[(size_t)arow * 128 + t * 32 + kg * 8];
            float4 u0 = xp[0], u1 = xp[1];
            f16x8 a;
            a[0] = (_Float16)u0.x; a[1] = (_Float16)u0.y;
            a[2] = (_Float16)u0.z; a[3] = (_Float16)u0.w;
            a[4] = (_Float16)u1.x; a[5] = (_Float16)u1.y;
            a[6] = (_Float16)u1.z; a[7] = (_Float16)u1.w;
#pragma unroll
            for (int u = 0; u < 2; ++u)
                acc[u] = __builtin_amdgcn_mfma_f32_16x16x32_f16(a, b[t][u], acc[u], 0, 0, 0);
        }

        float ds[4];
#pragma unroll
        for (int r = 0; r < 4; ++r)
            ds[r] = rsqrtf((float)(deg32[(slab * 16 + kg * 4 + r) << 4] + 1));

#pragma unroll
        for (int u = 0; u < 2; ++u) {
            int col = colbase + u * 16 + lo;
#pragma unroll
            for (int r = 0; r < 4; ++r) {
                int row = slab * 16 + kg * 4 + r;
                G[(size_t)row * 128 + col] = (_Float16)(acc[u][r] * ds[r]);
            }
        }
    }
}

// ---------------------------------------------------------------------------
// Fused aggregation + next-layer GEMM. 1024 threads = 16 waves.
// Wave w aggregates node blockIdx*16+w (1 node/wave, full-row 4B/lane
// gathers) -> LDS As[16][136]; then BN/16 waves run the 16-row MFMA slab
// with the dis-scaled epilogue. N % 16 == 0.
// ---------------------------------------------------------------------------
template <int BN>
__global__ __launch_bounds__(1024, 8) void k_aggr_gemm(
    const int* __restrict__ deg32, const unsigned short* __restrict__ ell,
    const __half* __restrict__ gin, const float* __restrict__ bias,
    const float* __restrict__ W, _Float16* __restrict__ gout, int N) {
    __shared__ _Float16 As[16][136];

    const int wv = threadIdx.x >> 6;   // 0..15
    const int lane = threadIdx.x & 63;

    if (blockIdx.x == 0 && threadIdx.x < BN / 2)
        ((int*)(gout + (size_t)N * BN))[threadIdx.x] = 0;  // zero row N

    const int base = blockIdx.x * 16;
    const int wid = base + wv;
    {
        int d = deg32[wid << 4];
        int dc = min(d, 64);
        int dp = (dc + 15) & ~15;

        const __half2* gp = (const __half2*)gin;
        float2 self = __half22float2(gp[(size_t)wid * 64 + lane]);

        const uint4* rowq = (const uint4*)&ell[(size_t)wid * 64];
        __half2 s0 = __float2half2_rn(0.f), s1 = s0, s2 = s0, s3 = s0;

        for (int j = 0; j < dp; j += 16) {
            uint4 r0 = rowq[j >> 3];
            uint4 r1 = rowq[(j >> 3) + 1];
            unsigned w[8] = {r0.x, r0.y, r0.z, r0.w, r1.x, r1.y, r1.z, r1.w};
            __half2 v[16];
#pragma unroll
            for (int t = 0; t < 16; ++t) {
                unsigned idx = (w[t >> 1] >> ((t & 1) * 16)) & 0xFFFFu;
                v[t] = gp[(size_t)idx * 64 + lane];
            }
#pragma unroll
            for (int t = 0; t < 16; t += 4) {
                s0 = __hadd2(s0, v[t + 0]);
                s1 = __hadd2(s1, v[t + 1]);
                s2 = __hadd2(s2, v[t + 2]);
                s3 = __hadd2(s3, v[t + 3]);
            }
        }

        float2 a0 = __half22float2(s0), a1 = __half22float2(s1);
        float2 a2 = __half22float2(s2), a3 = __half22float2(s3);
        float ax = self.x + (a0.x + a1.x) + (a2.x + a3.x);
        float ay = self.y + (a0.y + a1.y) + (a2.y + a3.y);

        float di = rsqrtf((float)(d + 1));
        float2 bv = *(const float2*)&bias[lane * 2];
        ax = fmaxf(di * ax + bv.x, 0.f);
        ay = fmaxf(di * ay + bv.y, 0.f);
        ((__half2*)&As[wv][0])[lane] = __float22half2_rn(make_float2(ax, ay));
    }
    __syncthreads();

    if (wv < BN / 16) {
        const int lo = lane & 15;
        const int kg = lane >> 4;
        const int col = wv * 16 + lo;

        f16x8 b[4];
#pragma unroll
        for (int t = 0; t < 4; ++t)
#pragma unroll
            for (int j = 0; j < 8; ++j)
                b[t][j] = (_Float16)W[(size_t)(t * 32 + kg * 8 + j) * BN + col];

        f32x4 acc = (f32x4)0.0f;
#pragma unroll
        for (int t = 0; t < 4; ++t) {
            f16x8 a = *(const f16x8*)&As[lo][t * 32 + kg * 8];
            acc = __builtin_amdgcn_mfma_f32_16x16x32_f16(a, b[t], acc, 0, 0, 0);
        }

#pragma unroll
        for (int r = 0; r < 4; ++r) {
            int row = base + kg * 4 + r;
            float ds = rsqrtf((float)(deg32[row << 4] + 1));
            gout[(size_t)row * BN + col] = (_Float16)(acc[r] * ds);
        }
    }
}

// ---------------------------------------------------------------------------
// Final aggregation (F=64): two nodes per wave (32 lanes x half2), fp32 out.
// ---------------------------------------------------------------------------
__global__ __launch_bounds__(256) void k_aggr_final(const int* __restrict__ deg32,
                                                    const unsigned short* __restrict__ ell,
                                                    const __half* __restrict__ g,
                                                    const float* __restrict__ bias,
                                                    float* __restrict__ out, int N) {
    int wid = blockIdx.x * 8 + (threadIdx.x >> 5);
    int sub = threadIdx.x & 31;
    if (wid >= N) return;
    int d = deg32[wid << 4];
    int dc = min(d, 64);
    int dp = (dc + 15) & ~15;

    const __half2* gp = (const __half2*)g;  // 32 half2 per 64-wide row
    float2 self = __half22float2(gp[(size_t)wid * 32 + sub]);

    const uint4* rowq = (const uint4*)&ell[(size_t)wid * 64];
    __half2 s0 = __float2half2_rn(0.f), s1 = s0, s2 = s0, s3 = s0;

    for (int j = 0; j < dp; j += 16) {
        uint4 r0 = rowq[j >> 3];
        uint4 r1 = rowq[(j >> 3) + 1];
        unsigned w[8] = {r0.x, r0.y, r0.z, r0.w, r1.x, r1.y, r1.z, r1.w};
        __half2 v[16];
#pragma unroll
        for (int t = 0; t < 16; ++t) {
            unsigned idx = (w[t >> 1] >> ((t & 1) * 16)) & 0xFFFFu;
            v[t] = gp[(size_t)idx * 32 + sub];
        }
#pragma unroll
        for (int t = 0; t < 16; t += 4) {
            s0 = __hadd2(s0, v[t + 0]);
            s1 = __hadd2(s1, v[t + 1]);
            s2 = __hadd2(s2, v[t + 2]);
            s3 = __hadd2(s3, v[t + 3]);
        }
    }

    float2 a0 = __half22float2(s0), a1 = __half22float2(s1);
    float2 a2 = __half22float2(s2), a3 = __half22float2(s3);
    float ax = self.x + (a0.x + a1.x) + (a2.x + a3.x);
    float ay = self.y + (a0.y + a1.y) + (a2.y + a3.y);

    float di = rsqrtf((float)(d + 1));
    float2 bv = *(const float2*)&bias[sub * 2];
    float2 o;
    o.x = di * ax + bv.x;
    o.y = di * ay + bv.y;
    *(float2*)&out[(size_t)wid * 64 + sub * 2] = o;
}

extern "C" void kernel_launch(void* const* d_in, const int* in_sizes, int n_in,
                              void* d_out, int out_size, void* d_ws, size_t ws_size,
                              hipStream_t stream) {
    const float* x = (const float*)d_in[0];
    const int* ei = (const int*)d_in[1];
    const float* W1 = (const float*)d_in[2];
    const float* b1 = (const float*)d_in[3];
    const float* W2 = (const float*)d_in[4];
    const float* b2 = (const float*)d_in[5];
    const float* W3 = (const float*)d_in[6];
    const float* b3 = (const float*)d_in[7];

    const int N = in_sizes[0] / 128;  // 50000
    const int E = in_sizes[1] / 2;    // 640000
    const int* src = ei;
    const int* dst = ei + E;

    auto align512 = [](size_t v) { return (v + 511) & ~(size_t)511; };
    char* p = (char*)d_ws;
    int* deg32 = (int*)p;                      p += align512((size_t)(N + 1) * 16 * 4);
    unsigned short* ell = (unsigned short*)p;  p += align512((size_t)N * 64 * 2);
    __half* bufA = (__half*)p;                 p += align512((size_t)(N + 1) * 128 * 2);
    __half* bufB = (__half*)p;

    // 1) zero padded degree counters + sentinel-fill ELL
    int nDeg = (N + 1) * 16;
    int nEllw = N * 32;  // ELL dwords
    unsigned int pat = ((unsigned)N << 16) | (unsigned)N;
    int initThreads = nDeg > nEllw ? nDeg : nEllw;
    k_init<<<(initThreads + 255) / 256, 256, 0, stream>>>(deg32, nDeg,
                                                          (unsigned int*)ell, nEllw, pat);
    // 2) ELL fill, XCD-partitioned (grid multiple of 8)
    k_ellfill<<<2048, 256, 0, stream>>>(src, dst, deg32, ell, E);
    // 3) gemm1: g1 = dis .* (x@W1) -> bufA
    k_gemm1<<<512, 256, 0, stream>>>(x, W1, deg32, (_Float16*)bufA, N);
    // 4) fused aggr1 + gemm2 -> bufB
    k_aggr_gemm<128><<<N / 16, 1024, 0, stream>>>(deg32, ell, bufA, b1, W2,
                                                  (_Float16*)bufB, N);
    // 5) fused aggr2 + gemm3 -> bufA (64-wide)
    k_aggr_gemm<64><<<N / 16, 1024, 0, stream>>>(deg32, ell, bufB, b2, W3,
                                                 (_Float16*)bufA, N);
    // 6) final aggregation -> fp32 output
    k_aggr_final<<<(N + 7) / 8, 256, 0, stream>>>(deg32, ell, bufA, b3,
                                                  (float*)d_out, N);
}